// Round 11
// baseline (198.913 us; speedup 1.0000x reference)
//
#include <hip/hip_runtime.h>
#include <hip/hip_bf16.h>

typedef float f32x4 __attribute__((ext_vector_type(4)));
typedef float f32x16 __attribute__((ext_vector_type(16)));
typedef short bf16x8 __attribute__((ext_vector_type(8)));

#define NSEQ 2048
#define CDIM 1024
#define NHEAD 16
#define HDIM 64
#define MROWS 4096
// scale(1/8) * log2(e) folded into Q at projection epilogue
#define QSCALE 0.18033688011f
// defer-max threshold: 8 / ln(2) (P bounded by e^8)
#define DEFER_THR 11.5416f

__device__ __forceinline__ unsigned short f2bf(float f) {
    unsigned int u = __builtin_bit_cast(unsigned int, f);
    u += 0x7FFFu + ((u >> 16) & 1u);
    return (unsigned short)(u >> 16);
}

__device__ __forceinline__ unsigned pkbf(float lo, float hi_) {
    unsigned r;
    asm("v_cvt_pk_bf16_f32 %0, %1, %2" : "=v"(r) : "v"(lo), "v"(hi_));
    return r;
}

// ---------------- all f32->bf16 conversions in ONE launch ----------------
__global__ __launch_bounds__(256) void cvt6_kernel(
    const float* __restrict__ q, const float* __restrict__ k, const float* __restrict__ v,
    const float* __restrict__ wq, const float* __restrict__ wk, const float* __restrict__ wv,
    unsigned short* __restrict__ dq, unsigned short* __restrict__ dk, unsigned short* __restrict__ dv,
    unsigned short* __restrict__ dwq, unsigned short* __restrict__ dwk, unsigned short* __restrict__ dwv)
{
    int b = blockIdx.x;
    const float* s; unsigned short* d; int base;
    if (b < 4096)       { s = q;  d = dq;  base = b; }
    else if (b < 8192)  { s = k;  d = dk;  base = b - 4096; }
    else if (b < 12288) { s = v;  d = dv;  base = b - 8192; }
    else if (b < 13312) { s = wq; d = dwq; base = b - 12288; }
    else if (b < 14336) { s = wk; d = dwk; base = b - 13312; }
    else                { s = wv; d = dwv; base = b - 14336; }
    int i = (base * 256 + threadIdx.x) * 4;
    float4 t4 = *reinterpret_cast<const float4*>(s + i);
    ushort4 o;
    o.x = f2bf(t4.x); o.y = f2bf(t4.y); o.z = f2bf(t4.z); o.w = f2bf(t4.w);
    *reinterpret_cast<ushort4*>(d + i) = o;
}

// ---------------- fused projection GEMM + bias + RoPE -------------------
// r8-proven structure: padded LDS [128][72], bf16x8 VALU staging
__global__ __launch_bounds__(256) void gemm_rope_kernel(
    const unsigned short* __restrict__ Xq, const unsigned short* __restrict__ Xk,
    const unsigned short* __restrict__ Xv,
    const unsigned short* __restrict__ Wqb, const unsigned short* __restrict__ Wkb,
    const unsigned short* __restrict__ Wvb,
    const float* __restrict__ bq, const float* __restrict__ bk, const float* __restrict__ bv,
    const float* __restrict__ qcos, const float* __restrict__ qsin,
    const float* __restrict__ kcos, const float* __restrict__ ksin,
    unsigned short* __restrict__ Qh, unsigned short* __restrict__ Kh,
    unsigned short* __restrict__ VT)
{
    __shared__ unsigned short Al[128][72];
    __shared__ unsigned short Bl[128][72];

    const int tid  = threadIdx.x;
    const int wave = tid >> 6;
    const int lane = tid & 63;
    const int lr   = lane & 15;
    const int lg   = lane >> 4;
    const int lk   = lg * 8;
    const int wm   = wave >> 1;
    const int wn   = wave & 1;
    const int m0   = blockIdx.y * 128;
    const int j0   = blockIdx.x * 128;
    const int z    = blockIdx.z;

    const unsigned short* X = (z == 0) ? Xq : (z == 1) ? Xk : Xv;
    const unsigned short* W = (z == 0) ? Wqb : (z == 1) ? Wkb : Wvb;
    const float* bias = (z == 0) ? bq : (z == 1) ? bk : bv;
    const float* cosb = (z == 0) ? qcos : kcos;
    const float* sinb = (z == 0) ? qsin : ksin;

    f32x4 acc[4][4];
    const f32x4 zero4 = {0.f, 0.f, 0.f, 0.f};
    #pragma unroll
    for (int a = 0; a < 4; a++)
        #pragma unroll
        for (int b = 0; b < 4; b++) acc[a][b] = zero4;

    for (int k0 = 0; k0 < CDIM; k0 += 64) {
        __syncthreads();
        #pragma unroll
        for (int it = 0; it < 4; it++) {
            int c = tid + it * 256;
            int row = c >> 3, col = (c & 7) << 3;
            *reinterpret_cast<bf16x8*>(&Al[row][col]) =
                *reinterpret_cast<const bf16x8*>(X + (size_t)(m0 + row) * CDIM + k0 + col);
            *reinterpret_cast<bf16x8*>(&Bl[row][col]) =
                *reinterpret_cast<const bf16x8*>(W + (size_t)(j0 + row) * CDIM + k0 + col);
        }
        __syncthreads();
        #pragma unroll
        for (int ks = 0; ks < 2; ks++) {
            bf16x8 af[4], bfm[4];
            #pragma unroll
            for (int mi = 0; mi < 4; mi++)
                af[mi] = *reinterpret_cast<const bf16x8*>(&Al[wm * 64 + 16 * mi + lr][ks * 32 + lk]);
            #pragma unroll
            for (int ni = 0; ni < 4; ni++)
                bfm[ni] = *reinterpret_cast<const bf16x8*>(&Bl[wn * 64 + 16 * ni + lr][ks * 32 + lk]);
            #pragma unroll
            for (int mi = 0; mi < 4; mi++)
                #pragma unroll
                for (int ni = 0; ni < 4; ni++)
                    acc[mi][ni] = __builtin_amdgcn_mfma_f32_16x16x32_bf16(
                        af[mi], bfm[ni], acc[mi][ni], 0, 0, 0);
        }
    }

    #pragma unroll
    for (int mi = 0; mi < 4; mi++) {
        const int mbase = m0 + wm * 64 + 16 * mi + 4 * lg;
        #pragma unroll
        for (int ni = 0; ni < 4; ni++) {
            const int j  = j0 + wn * 64 + 16 * ni + lr;
            const float bj = bias[j];
            if (z == 2) {
                const int b = mbase >> 11, n = mbase & 2047;
                const int h = j >> 6, d = j & 63;
                ushort4 pk;
                pk.x = f2bf(acc[mi][ni][0] + bj);
                pk.y = f2bf(acc[mi][ni][1] + bj);
                pk.z = f2bf(acc[mi][ni][2] + bj);
                pk.w = f2bf(acc[mi][ni][3] + bj);
                *reinterpret_cast<ushort4*>(VT + ((size_t)((b * NHEAD + h) * HDIM + d) << 11) + n) = pk;
            } else {
                unsigned short* Out = (z == 0) ? Qh : Kh;
                const float scl = (z == 0) ? QSCALE : 1.0f;
                const int hi = (j & 63) >> 1;
                const float sg = (j & 1) ? 1.f : -1.f;
                float vv[4], pp[4];
                #pragma unroll
                for (int r = 0; r < 4; r++) vv[r] = acc[mi][ni][r] + bj;
                #pragma unroll
                for (int r = 0; r < 4; r++) pp[r] = __shfl_xor(vv[r], 1);
                #pragma unroll
                for (int r = 0; r < 4; r++) {
                    const int m = mbase + r;
                    const int b = m >> 11, n = m & 2047;
                    const float c = cosb[n * 32 + hi];
                    const float s = sinb[n * 32 + hi];
                    const float ov = fmaf(vv[r], c, pp[r] * (sg * s)) * scl;
                    Out[((size_t)((b * NHEAD + (j >> 6)) * NSEQ + n) << 6) + (j & 63)] = f2bf(ov);
                }
            }
        }
    }
}

// ---------------- flash attention: NO LDS, direct global fragments -------
// grid (32 heads, 16 qtiles, 2 halves). block 256 = 4 independent waves,
// each 32 q-rows. Both K (A-op: 8 contig d at fixed key) and V^T (B-op:
// 8 contig keys at fixed d) fragments are 16B-contiguous in global ->
// load straight to VGPRs. Zero barriers, zero LDS; K/V L2-resident via
// head-on-XCD pinning. Softmax identical to round-8 (proven).
__global__ __launch_bounds__(256, 4) void attn_kernel(
    const unsigned short* __restrict__ Qh, const unsigned short* __restrict__ Kh,
    const unsigned short* __restrict__ VT, float* __restrict__ out,
    float* __restrict__ O2, float2* __restrict__ ML)
{
    const int tid  = threadIdx.x;
    const int wave = tid >> 6;
    const int lane = tid & 63;
    const int c    = lane & 31;
    const int hi   = lane >> 5;
    const int bh   = blockIdx.x;             // head on x: XCD = head % 8
    const int q0w  = blockIdx.y * 128 + wave * 32;
    const int half = blockIdx.z;
    const int kbase = half * 1024;

    const unsigned short* Qb = Qh + (size_t)bh * NSEQ * HDIM;
    const char* Kb = (const char*)(Kh + (size_t)bh * NSEQ * HDIM);
    const char* Vb = (const char*)(VT + (size_t)bh * HDIM * NSEQ);

    // Q as B-operand: lane holds Q[d = 16s+8hi+j][q = q0w+c] (pre-scaled)
    bf16x8 qf[4];
    #pragma unroll
    for (int s = 0; s < 4; s++)
        qf[s] = *reinterpret_cast<const bf16x8*>(
            Qb + (size_t)(q0w + c) * HDIM + s * 16 + hi * 8);

    const f32x16 z16 = {0,0,0,0,0,0,0,0,0,0,0,0,0,0,0,0};
    f32x16 o0 = z16, o1 = z16;
    float mrun = -1e30f, lrun = 0.f;

    // per-lane fragment base addresses
    // K row (key = kbase + c + 32t): 8 d-elems at si*16 + hi*8
    const char* kp  = Kb + (size_t)(kbase + c) * 128 + hi * 16;
    // V^T row d = c (o0) / d = c+32 (o1): 8 keys at kbase + 32t + u*16 + hi*8
    const char* vp0 = Vb + (size_t)c * (NSEQ * 2) + (size_t)kbase * 2 + hi * 16;
    const char* vp1 = vp0 + (size_t)32 * (NSEQ * 2);

    #pragma unroll 2
    for (int t = 0; t < 32; ++t) {
        const char* kt  = kp  + (size_t)t * (32 * 128);
        const char* vt0 = vp0 + t * 64;
        const char* vt1 = vp1 + t * 64;

        bf16x8 kf0 = *reinterpret_cast<const bf16x8*>(kt);
        bf16x8 kf1 = *reinterpret_cast<const bf16x8*>(kt + 32);
        bf16x8 kf2 = *reinterpret_cast<const bf16x8*>(kt + 64);
        bf16x8 kf3 = *reinterpret_cast<const bf16x8*>(kt + 96);
        bf16x8 va0 = *reinterpret_cast<const bf16x8*>(vt0);
        bf16x8 va1 = *reinterpret_cast<const bf16x8*>(vt0 + 32);
        bf16x8 vb0 = *reinterpret_cast<const bf16x8*>(vt1);
        bf16x8 vb1 = *reinterpret_cast<const bf16x8*>(vt1 + 32);

        // S^T = mfma(K, Q): lane holds S[key = crow(r,hi)][q = c], 32 keys
        f32x16 s = z16;
        __builtin_amdgcn_s_setprio(1);
        s = __builtin_amdgcn_mfma_f32_32x32x16_bf16(kf0, qf[0], s, 0, 0, 0);
        s = __builtin_amdgcn_mfma_f32_32x32x16_bf16(kf1, qf[1], s, 0, 0, 0);
        s = __builtin_amdgcn_mfma_f32_32x32x16_bf16(kf2, qf[2], s, 0, 0, 0);
        s = __builtin_amdgcn_mfma_f32_32x32x16_bf16(kf3, qf[3], s, 0, 0, 0);
        __builtin_amdgcn_s_setprio(0);

        // row max: 15 in-lane + partner exchange
        float tmx[8];
        #pragma unroll
        for (int i = 0; i < 8; i++) tmx[i] = fmaxf(s[2 * i], s[2 * i + 1]);
        float tm = fmaxf(fmaxf(fmaxf(tmx[0], tmx[1]), fmaxf(tmx[2], tmx[3])),
                         fmaxf(fmaxf(tmx[4], tmx[5]), fmaxf(tmx[6], tmx[7])));
        tm = fmaxf(tm, __shfl_xor(tm, 32));

        // defer-max: rescale only when a row max grew past threshold
        if (!__all(tm - mrun <= DEFER_THR)) {
            const float mnew  = fmaxf(mrun, tm);
            const float alpha = exp2f(mrun - mnew);
            mrun = mnew;
            lrun *= alpha;
            #pragma unroll
            for (int r = 0; r < 16; r++) {
                const float ar = __shfl(alpha, (r & 3) + 8 * (r >> 2) + 4 * hi);
                o0[r] *= ar;
                o1[r] *= ar;
            }
        }

        // P = exp2(S - m), row sum
        #pragma unroll
        for (int r = 0; r < 16; r++) s[r] = exp2f(s[r] - mrun);
        float rsx[8];
        #pragma unroll
        for (int i = 0; i < 8; i++) rsx[i] = s[2 * i] + s[2 * i + 1];
        float rs = ((rsx[0] + rsx[1]) + (rsx[2] + rsx[3])) +
                   ((rsx[4] + rsx[5]) + (rsx[6] + rsx[7]));
        rs += __shfl_xor(rs, 32);
        lrun += rs;

        // P -> A-fragments in-register: cvt_pk pairs + permlane32_swap
        unsigned pw[2][4];
        #pragma unroll
        for (int u = 0; u < 2; u++) {
            const int b = u * 8;
            unsigned x0 = pkbf(s[b + 0], s[b + 1]);
            unsigned y0 = pkbf(s[b + 4], s[b + 5]);
            asm("v_permlane32_swap_b32 %0, %1" : "+v"(x0), "+v"(y0));
            unsigned x1 = pkbf(s[b + 2], s[b + 3]);
            unsigned y1 = pkbf(s[b + 6], s[b + 7]);
            asm("v_permlane32_swap_b32 %0, %1" : "+v"(x1), "+v"(y1));
            pw[u][0] = x0; pw[u][1] = x1; pw[u][2] = y0; pw[u][3] = y1;
        }

        // O += P V  (o0: d 0..31, o1: d 32..63)
        __builtin_amdgcn_s_setprio(1);
        {
            uint4 w0; w0.x = pw[0][0]; w0.y = pw[0][1]; w0.z = pw[0][2]; w0.w = pw[0][3];
            bf16x8 pa0 = __builtin_bit_cast(bf16x8, w0);
            o0 = __builtin_amdgcn_mfma_f32_32x32x16_bf16(pa0, va0, o0, 0, 0, 0);
            o1 = __builtin_amdgcn_mfma_f32_32x32x16_bf16(pa0, vb0, o1, 0, 0, 0);
            uint4 w1; w1.x = pw[1][0]; w1.y = pw[1][1]; w1.z = pw[1][2]; w1.w = pw[1][3];
            bf16x8 pa1 = __builtin_bit_cast(bf16x8, w1);
            o0 = __builtin_amdgcn_mfma_f32_32x32x16_bf16(pa1, va1, o0, 0, 0, 0);
            o1 = __builtin_amdgcn_mfma_f32_32x32x16_bf16(pa1, vb1, o1, 0, 0, 0);
        }
        __builtin_amdgcn_s_setprio(0);
    }

    // epilogue: write UNNORMALIZED partial O + per-row (m,l)
    float* obase = half ? O2 : out;
    const int b = bh >> 4, h = bh & 15;
    #pragma unroll
    for (int r = 0; r < 16; r++) {
        const int qrow = (r & 3) + 8 * (r >> 2) + 4 * hi;
        const int n = q0w + qrow;
        float* op = obase + ((size_t)(b * NSEQ + n) << 10) + h * HDIM + c;
        op[0]  = o0[r];
        op[32] = o1[r];
    }
    if (hi == 0)
        ML[((size_t)half * 32 + bh) * NSEQ + q0w + c] = make_float2(mrun, lrun);
}

// ---------------- combine the two KV halves (memory-bound) ---------------
__global__ __launch_bounds__(256) void attn_combine(
    float* __restrict__ out, const float* __restrict__ O2,
    const float2* __restrict__ ML)
{
    const int idx4 = blockIdx.x * 256 + threadIdx.x;   // float4 index
    const int e    = idx4 * 4;
    const int row  = e >> 10;          // b*2048+n
    const int col  = e & 1023;
    const int h    = col >> 6;
    const int b    = row >> 11;
    const int n    = row & 2047;
    const int bh   = b * NHEAD + h;

    const float2 ml1 = ML[(size_t)bh * NSEQ + n];
    const float2 ml2 = ML[((size_t)32 + bh) * NSEQ + n];
    const float M  = fmaxf(ml1.x, ml2.x);
    const float w1 = exp2f(ml1.x - M);
    const float w2 = exp2f(ml2.x - M);
    const float inv = 1.0f / (w1 * ml1.y + w2 * ml2.y);

    float4 a = reinterpret_cast<float4*>(out)[idx4];
    float4 d = reinterpret_cast<const float4*>(O2)[idx4];
    float4 r;
    r.x = (w1 * a.x + w2 * d.x) * inv;
    r.y = (w1 * a.y + w2 * d.y) * inv;
    r.z = (w1 * a.z + w2 * d.z) * inv;
    r.w = (w1 * a.w + w2 * d.w) * inv;
    reinterpret_cast<float4*>(out)[idx4] = r;
}

extern "C" void kernel_launch(void* const* d_in, const int* in_sizes, int n_in,
                              void* d_out, int out_size, void* d_ws, size_t ws_size,
                              hipStream_t stream) {
    const float* q    = (const float*)d_in[0];
    const float* k    = (const float*)d_in[1];
    const float* v    = (const float*)d_in[2];
    const float* qcos = (const float*)d_in[3];
    const float* qsin = (const float*)d_in[4];
    const float* kcos = (const float*)d_in[5];
    const float* ksin = (const float*)d_in[6];
    const float* Wq   = (const float*)d_in[7];
    const float* bq   = (const float*)d_in[8];
    const float* Wk   = (const float*)d_in[9];
    const float* bk   = (const float*)d_in[10];
    const float* Wv   = (const float*)d_in[11];
    const float* bv   = (const float*)d_in[12];
    float* out = (float*)d_out;

    unsigned short* Xqb = (unsigned short*)d_ws;
    unsigned short* Xkb = Xqb + (size_t)MROWS * CDIM;
    unsigned short* Xvb = Xkb + (size_t)MROWS * CDIM;
    unsigned short* Wqb = Xvb + (size_t)MROWS * CDIM;
    unsigned short* Wkb = Wqb + (size_t)CDIM * CDIM;
    unsigned short* Wvb = Wkb + (size_t)CDIM * CDIM;
    unsigned short* Qhb = Wvb + (size_t)CDIM * CDIM;
    unsigned short* Khb = Qhb + (size_t)MROWS * CDIM;
    unsigned short* VTb = Khb + (size_t)MROWS * CDIM;

    // dead-after-gemm region reuse: O2 (16MB) over Xqb/Xkb, ML (1MB) in Xvb
    float*  O2 = (float*)Xqb;
    float2* ML = (float2*)((char*)d_ws + (size_t)16 * 1024 * 1024);

    cvt6_kernel<<<15360, 256, 0, stream>>>(q, k, v, Wq, Wk, Wv,
                                           Xqb, Xkb, Xvb, Wqb, Wkb, Wvb);

    dim3 gg(CDIM / 128, MROWS / 128, 3);
    gemm_rope_kernel<<<gg, 256, 0, stream>>>(Xqb, Xkb, Xvb, Wqb, Wkb, Wvb,
                                             bq, bk, bv, qcos, qsin, kcos, ksin,
                                             Qhb, Khb, VTb);

    attn_kernel<<<dim3(2 * NHEAD, NSEQ / 128, 2), 256, 0, stream>>>(
        Qhb, Khb, VTb, out, O2, ML);

    attn_combine<<<(MROWS * CDIM / 4) / 256, 256, 0, stream>>>(out, O2, ML);
}

// Round 12
// 141.661 us; speedup vs baseline: 1.4041x; 1.4041x over previous
//
#include <hip/hip_runtime.h>
#include <hip/hip_bf16.h>

typedef float f32x4 __attribute__((ext_vector_type(4)));
typedef float f32x16 __attribute__((ext_vector_type(16)));
typedef short bf16x8 __attribute__((ext_vector_type(8)));

#define NSEQ 2048
#define CDIM 1024
#define NHEAD 16
#define HDIM 64
#define MROWS 4096
// scale(1/8) * log2(e) folded into Q at projection epilogue
#define QSCALE 0.18033688011f
// defer-max threshold: 8 / ln(2) (P bounded by e^8)
#define DEFER_THR 11.5416f

__device__ __forceinline__ unsigned short f2bf(float f) {
    unsigned int u = __builtin_bit_cast(unsigned int, f);
    u += 0x7FFFu + ((u >> 16) & 1u);
    return (unsigned short)(u >> 16);
}

__device__ __forceinline__ unsigned pkbf(float lo, float hi_) {
    unsigned r;
    asm("v_cvt_pk_bf16_f32 %0, %1, %2" : "=v"(r) : "v"(lo), "v"(hi_));
    return r;
}

__device__ __forceinline__ void gload16(const void* g, void* l) {
    __builtin_amdgcn_global_load_lds(
        (const __attribute__((address_space(1))) unsigned int*)g,
        (__attribute__((address_space(3))) unsigned int*)l, 16, 0, 0);
}

// ---------------- all f32->bf16 conversions in ONE launch ----------------
__global__ __launch_bounds__(256) void cvt6_kernel(
    const float* __restrict__ q, const float* __restrict__ k, const float* __restrict__ v,
    const float* __restrict__ wq, const float* __restrict__ wk, const float* __restrict__ wv,
    unsigned short* __restrict__ dq, unsigned short* __restrict__ dk, unsigned short* __restrict__ dv,
    unsigned short* __restrict__ dwq, unsigned short* __restrict__ dwk, unsigned short* __restrict__ dwv)
{
    int b = blockIdx.x;
    const float* s; unsigned short* d; int base;
    if (b < 4096)       { s = q;  d = dq;  base = b; }
    else if (b < 8192)  { s = k;  d = dk;  base = b - 4096; }
    else if (b < 12288) { s = v;  d = dv;  base = b - 8192; }
    else if (b < 13312) { s = wq; d = dwq; base = b - 12288; }
    else if (b < 14336) { s = wk; d = dwk; base = b - 13312; }
    else                { s = wv; d = dwv; base = b - 14336; }
    int i = (base * 256 + threadIdx.x) * 4;
    float4 t4 = *reinterpret_cast<const float4*>(s + i);
    ushort4 o;
    o.x = f2bf(t4.x); o.y = f2bf(t4.y); o.z = f2bf(t4.z); o.w = f2bf(t4.w);
    *reinterpret_cast<ushort4*>(d + i) = o;
}

// ---------------- fused projection GEMM + bias + RoPE -------------------
// gload_lds staging for BOTH tiles, [128 rows][128B] with XOR swizzle:
// pre-swizzled source + linear dest + swizzled read (rule-21 involution):
// LDS[row][col] = global[row][col ^ ((row&7)<<4)]; fragment read applies
// the same XOR with row&7 == lr&7.
__global__ __launch_bounds__(256) void gemm_rope_kernel(
    const unsigned short* __restrict__ Xq, const unsigned short* __restrict__ Xk,
    const unsigned short* __restrict__ Xv,
    const unsigned short* __restrict__ Wqb, const unsigned short* __restrict__ Wkb,
    const unsigned short* __restrict__ Wvb,
    const float* __restrict__ bq, const float* __restrict__ bk, const float* __restrict__ bv,
    const float* __restrict__ qcos, const float* __restrict__ qsin,
    const float* __restrict__ kcos, const float* __restrict__ ksin,
    unsigned short* __restrict__ Qh, unsigned short* __restrict__ Kh,
    unsigned short* __restrict__ VT)
{
    __shared__ unsigned char Asm[16384];   // [128 m][128B k], swizzled
    __shared__ unsigned char Bsm[16384];   // [128 j][128B k], swizzled

    const int tid  = threadIdx.x;
    const int wave = tid >> 6;
    const int lane = tid & 63;
    const int lr   = lane & 15;
    const int lg   = lane >> 4;
    const int wm   = wave >> 1;
    const int wn   = wave & 1;
    const int m0   = blockIdx.y * 128;
    const int j0   = blockIdx.x * 128;
    const int z    = blockIdx.z;

    const unsigned short* X = (z == 0) ? Xq : (z == 1) ? Xk : Xv;
    const unsigned short* W = (z == 0) ? Wqb : (z == 1) ? Wkb : Wvb;
    const float* bias = (z == 0) ? bq : (z == 1) ? bk : bv;
    const float* cosb = (z == 0) ? qcos : kcos;
    const float* sinb = (z == 0) ? qsin : ksin;

    // staging: chunk ch = wave*4+i covers rows [ch*8,+8); within a chunk the
    // HW writes linearly (base + lane*16) -> row = ch*8 + (lane>>3),
    // col = (lane&7)*16. Source column pre-swizzled by ((row&7)<<4).
    const int sr7 = lane >> 3;
    const int scb = ((lane & 7) * 16) ^ (sr7 << 4);
    const int fsw = (lr & 7) << 4;          // fragment read swizzle

    f32x4 acc[4][4];
    const f32x4 zero4 = {0.f, 0.f, 0.f, 0.f};
    #pragma unroll
    for (int a = 0; a < 4; a++)
        #pragma unroll
        for (int b = 0; b < 4; b++) acc[a][b] = zero4;

    for (int k0 = 0; k0 < CDIM; k0 += 64) {
        __syncthreads();
        #pragma unroll
        for (int i = 0; i < 4; i++) {
            const int ch  = wave * 4 + i;
            const int row = ch * 8 + sr7;
            gload16((const char*)X + (size_t)(m0 + row) * 2048 + k0 * 2 + scb,
                    Asm + ch * 1024);
            gload16((const char*)W + (size_t)(j0 + row) * 2048 + k0 * 2 + scb,
                    Bsm + ch * 1024);
        }
        __syncthreads();
        #pragma unroll
        for (int ks = 0; ks < 2; ks++) {
            bf16x8 af[4], bfm[4];
            #pragma unroll
            for (int mi = 0; mi < 4; mi++)
                af[mi] = *reinterpret_cast<const bf16x8*>(
                    &Asm[(wm * 64 + 16 * mi + lr) * 128 + ((ks * 64 + lg * 16) ^ fsw)]);
            #pragma unroll
            for (int ni = 0; ni < 4; ni++)
                bfm[ni] = *reinterpret_cast<const bf16x8*>(
                    &Bsm[(wn * 64 + 16 * ni + lr) * 128 + ((ks * 64 + lg * 16) ^ fsw)]);
            #pragma unroll
            for (int mi = 0; mi < 4; mi++)
                #pragma unroll
                for (int ni = 0; ni < 4; ni++)
                    acc[mi][ni] = __builtin_amdgcn_mfma_f32_16x16x32_bf16(
                        af[mi], bfm[ni], acc[mi][ni], 0, 0, 0);
        }
    }

    #pragma unroll
    for (int mi = 0; mi < 4; mi++) {
        const int mbase = m0 + wm * 64 + 16 * mi + 4 * lg;
        #pragma unroll
        for (int ni = 0; ni < 4; ni++) {
            const int j  = j0 + wn * 64 + 16 * ni + lr;
            const float bj = bias[j];
            if (z == 2) {
                const int b = mbase >> 11, n = mbase & 2047;
                const int h = j >> 6, d = j & 63;
                ushort4 pk;
                pk.x = f2bf(acc[mi][ni][0] + bj);
                pk.y = f2bf(acc[mi][ni][1] + bj);
                pk.z = f2bf(acc[mi][ni][2] + bj);
                pk.w = f2bf(acc[mi][ni][3] + bj);
                *reinterpret_cast<ushort4*>(VT + ((size_t)((b * NHEAD + h) * HDIM + d) << 11) + n) = pk;
            } else {
                unsigned short* Out = (z == 0) ? Qh : Kh;
                const float scl = (z == 0) ? QSCALE : 1.0f;
                const int hi = (j & 63) >> 1;
                const float sg = (j & 1) ? 1.f : -1.f;
                float vv[4], pp[4];
                #pragma unroll
                for (int r = 0; r < 4; r++) vv[r] = acc[mi][ni][r] + bj;
                #pragma unroll
                for (int r = 0; r < 4; r++) pp[r] = __shfl_xor(vv[r], 1);
                #pragma unroll
                for (int r = 0; r < 4; r++) {
                    const int m = mbase + r;
                    const int b = m >> 11, n = m & 2047;
                    const float c = cosb[n * 32 + hi];
                    const float s = sinb[n * 32 + hi];
                    const float ov = fmaf(vv[r], c, pp[r] * (sg * s)) * scl;
                    Out[((size_t)((b * NHEAD + (j >> 6)) * NSEQ + n) << 6) + (j & 63)] = f2bf(ov);
                }
            }
        }
    }
}

// ---------------- flash attention, KVBLK=32, low-register (r8 verbatim) --
__global__ __launch_bounds__(256, 4) void attn_kernel(
    const unsigned short* __restrict__ Qh, const unsigned short* __restrict__ Kh,
    const unsigned short* __restrict__ VT, float* __restrict__ out,
    float* __restrict__ O2, float2* __restrict__ ML)
{
    __shared__ unsigned char Ksm[2][4096];
    __shared__ unsigned char Vsm[2][4096];

    const int tid  = threadIdx.x;
    const int wave = tid >> 6;
    const int lane = tid & 63;
    const int c    = lane & 31;
    const int hi   = lane >> 5;
    const int bh   = blockIdx.x;             // head on x: XCD = head % 8
    const int q0w  = blockIdx.y * 128 + wave * 32;
    const int half = blockIdx.z;
    const int kbase = half * 1024;
    const int sw   = (c & 7) << 4;           // read-side XOR swizzle

    const unsigned short* Qb = Qh + (size_t)bh * NSEQ * HDIM;
    const char* Kb = (const char*)(Kh + (size_t)bh * NSEQ * HDIM);
    const char* Vb = (const char*)(VT + (size_t)bh * HDIM * NSEQ);

    // Q as B-operand: lane holds Q[d = 16s+8hi+j][q = q0w+c] (pre-scaled)
    bf16x8 qf[4];
    #pragma unroll
    for (int s = 0; s < 4; s++)
        qf[s] = *reinterpret_cast<const bf16x8*>(
            Qb + (size_t)(q0w + c) * HDIM + s * 16 + hi * 8);

    const f32x16 z16 = {0,0,0,0,0,0,0,0,0,0,0,0,0,0,0,0};
    f32x16 o0 = z16, o1 = z16;
    float mrun = -1e30f, lrun = 0.f;

    // staging per-thread constants: wave w stages 1KB of K + 1KB of V
    const int srow = wave * 8 + (lane >> 3);            // LDS row 0..31
    const int lb   = ((lane & 7) * 16) ^ ((srow & 7) << 4);  // logical byte
    const size_t skoff = (size_t)srow * 128 + lb;
    const int dv   = (lb & 64) ? (srow + 32) : srow;    // V d-row
    const size_t svoff = (size_t)dv * (NSEQ * 2) + (lb & 63);

    auto stage = [&](int buf, int n0) {
        gload16(Kb + (size_t)n0 * 128 + skoff, &Ksm[buf][wave * 1024]);
        gload16(Vb + (size_t)n0 * 2 + svoff, &Vsm[buf][wave * 1024]);
    };

    stage(0, kbase);
    __syncthreads();
    int cur = 0;

    for (int t = 0; t < 32; ++t) {
        if (t < 31) stage(cur ^ 1, kbase + (t + 1) * 32);

        // S^T = mfma(K, Q): lane holds S[key = crow(r,hi)][q = c], 32 keys
        f32x16 s = z16;
        __builtin_amdgcn_s_setprio(1);
        #pragma unroll
        for (int si = 0; si < 4; si++) {
            bf16x8 kf = *reinterpret_cast<const bf16x8*>(
                &Ksm[cur][c * 128 + ((si * 32 + hi * 16) ^ sw)]);
            s = __builtin_amdgcn_mfma_f32_32x32x16_bf16(kf, qf[si], s, 0, 0, 0);
        }
        __builtin_amdgcn_s_setprio(0);

        // row max: 15 in-lane + 1 partner exchange
        float tmx[8];
        #pragma unroll
        for (int i = 0; i < 8; i++) tmx[i] = fmaxf(s[2 * i], s[2 * i + 1]);
        float tm = fmaxf(fmaxf(fmaxf(tmx[0], tmx[1]), fmaxf(tmx[2], tmx[3])),
                         fmaxf(fmaxf(tmx[4], tmx[5]), fmaxf(tmx[6], tmx[7])));
        tm = fmaxf(tm, __shfl_xor(tm, 32));

        // defer-max: rescale only when a row max grew past threshold
        if (!__all(tm - mrun <= DEFER_THR)) {
            const float mnew  = fmaxf(mrun, tm);
            const float alpha = exp2f(mrun - mnew);
            mrun = mnew;
            lrun *= alpha;
            #pragma unroll
            for (int r = 0; r < 16; r++) {
                const float ar = __shfl(alpha, (r & 3) + 8 * (r >> 2) + 4 * hi);
                o0[r] *= ar;
                o1[r] *= ar;
            }
        }

        // P = exp2(S - m), row sum
        #pragma unroll
        for (int r = 0; r < 16; r++) s[r] = exp2f(s[r] - mrun);
        float rsx[8];
        #pragma unroll
        for (int i = 0; i < 8; i++) rsx[i] = s[2 * i] + s[2 * i + 1];
        float rs = ((rsx[0] + rsx[1]) + (rsx[2] + rsx[3])) +
                   ((rsx[4] + rsx[5]) + (rsx[6] + rsx[7]));
        rs += __shfl_xor(rs, 32);
        lrun += rs;

        // P -> A-fragments in-register: cvt_pk pairs + permlane32_swap
        unsigned pw[2][4];
        #pragma unroll
        for (int u = 0; u < 2; u++) {
            const int b = u * 8;
            unsigned x0 = pkbf(s[b + 0], s[b + 1]);
            unsigned y0 = pkbf(s[b + 4], s[b + 5]);
            asm("v_permlane32_swap_b32 %0, %1" : "+v"(x0), "+v"(y0));
            unsigned x1 = pkbf(s[b + 2], s[b + 3]);
            unsigned y1 = pkbf(s[b + 6], s[b + 7]);
            asm("v_permlane32_swap_b32 %0, %1" : "+v"(x1), "+v"(y1));
            pw[u][0] = x0; pw[u][1] = x1; pw[u][2] = y0; pw[u][3] = y1;
        }

        // O += P V  (o0: d 0..31, o1: d 32..63)
        __builtin_amdgcn_s_setprio(1);
        #pragma unroll
        for (int u = 0; u < 2; u++) {
            uint4 w;
            w.x = pw[u][0]; w.y = pw[u][1]; w.z = pw[u][2]; w.w = pw[u][3];
            bf16x8 pa = __builtin_bit_cast(bf16x8, w);
            bf16x8 vf0 = *reinterpret_cast<const bf16x8*>(
                &Vsm[cur][c * 128 + ((u * 32 + hi * 16) ^ sw)]);
            bf16x8 vf1 = *reinterpret_cast<const bf16x8*>(
                &Vsm[cur][c * 128 + ((64 + u * 32 + hi * 16) ^ sw)]);
            o0 = __builtin_amdgcn_mfma_f32_32x32x16_bf16(pa, vf0, o0, 0, 0, 0);
            o1 = __builtin_amdgcn_mfma_f32_32x32x16_bf16(pa, vf1, o1, 0, 0, 0);
        }
        __builtin_amdgcn_s_setprio(0);

        __syncthreads();
        cur ^= 1;
    }

    // epilogue: write UNNORMALIZED partial O + per-row (m,l)
    float* obase = half ? O2 : out;
    const int b = bh >> 4, h = bh & 15;
    #pragma unroll
    for (int r = 0; r < 16; r++) {
        const int qrow = (r & 3) + 8 * (r >> 2) + 4 * hi;
        const int n = q0w + qrow;
        float* op = obase + ((size_t)(b * NSEQ + n) << 10) + h * HDIM + c;
        op[0]  = o0[r];
        op[32] = o1[r];
    }
    if (hi == 0)
        ML[((size_t)half * 32 + bh) * NSEQ + q0w + c] = make_float2(mrun, lrun);
}

// ---------------- combine the two KV halves (memory-bound) ---------------
__global__ __launch_bounds__(256) void attn_combine(
    float* __restrict__ out, const float* __restrict__ O2,
    const float2* __restrict__ ML)
{
    const int idx4 = blockIdx.x * 256 + threadIdx.x;   // float4 index
    const int e    = idx4 * 4;
    const int row  = e >> 10;          // b*2048+n
    const int col  = e & 1023;
    const int h    = col >> 6;
    const int b    = row >> 11;
    const int n    = row & 2047;
    const int bh   = b * NHEAD + h;

    const float2 ml1 = ML[(size_t)bh * NSEQ + n];
    const float2 ml2 = ML[((size_t)32 + bh) * NSEQ + n];
    const float M  = fmaxf(ml1.x, ml2.x);
    const float w1 = exp2f(ml1.x - M);
    const float w2 = exp2f(ml2.x - M);
    const float inv = 1.0f / (w1 * ml1.y + w2 * ml2.y);

    float4 a = reinterpret_cast<float4*>(out)[idx4];
    float4 d = reinterpret_cast<const float4*>(O2)[idx4];
    float4 r;
    r.x = (w1 * a.x + w2 * d.x) * inv;
    r.y = (w1 * a.y + w2 * d.y) * inv;
    r.z = (w1 * a.z + w2 * d.z) * inv;
    r.w = (w1 * a.w + w2 * d.w) * inv;
    reinterpret_cast<float4*>(out)[idx4] = r;
}

extern "C" void kernel_launch(void* const* d_in, const int* in_sizes, int n_in,
                              void* d_out, int out_size, void* d_ws, size_t ws_size,
                              hipStream_t stream) {
    const float* q    = (const float*)d_in[0];
    const float* k    = (const float*)d_in[1];
    const float* v    = (const float*)d_in[2];
    const float* qcos = (const float*)d_in[3];
    const float* qsin = (const float*)d_in[4];
    const float* kcos = (const float*)d_in[5];
    const float* ksin = (const float*)d_in[6];
    const float* Wq   = (const float*)d_in[7];
    const float* bq   = (const float*)d_in[8];
    const float* Wk   = (const float*)d_in[9];
    const float* bk   = (const float*)d_in[10];
    const float* Wv   = (const float*)d_in[11];
    const float* bv   = (const float*)d_in[12];
    float* out = (float*)d_out;

    unsigned short* Xqb = (unsigned short*)d_ws;
    unsigned short* Xkb = Xqb + (size_t)MROWS * CDIM;
    unsigned short* Xvb = Xkb + (size_t)MROWS * CDIM;
    unsigned short* Wqb = Xvb + (size_t)MROWS * CDIM;
    unsigned short* Wkb = Wqb + (size_t)CDIM * CDIM;
    unsigned short* Wvb = Wkb + (size_t)CDIM * CDIM;
    unsigned short* Qhb = Wvb + (size_t)CDIM * CDIM;
    unsigned short* Khb = Qhb + (size_t)MROWS * CDIM;
    unsigned short* VTb = Khb + (size_t)MROWS * CDIM;

    // dead-after-gemm region reuse: O2 (16MB) over Xqb/Xkb, ML (1MB) in Xvb
    float*  O2 = (float*)Xqb;
    float2* ML = (float2*)((char*)d_ws + (size_t)16 * 1024 * 1024);

    cvt6_kernel<<<15360, 256, 0, stream>>>(q, k, v, Wq, Wk, Wv,
                                           Xqb, Xkb, Xvb, Wqb, Wkb, Wvb);

    dim3 gg(CDIM / 128, MROWS / 128, 3);
    gemm_rope_kernel<<<gg, 256, 0, stream>>>(Xqb, Xkb, Xvb, Wqb, Wkb, Wvb,
                                             bq, bk, bv, qcos, qsin, kcos, ksin,
                                             Qhb, Khb, VTb);

    attn_kernel<<<dim3(2 * NHEAD, NSEQ / 128, 2), 256, 0, stream>>>(
        Qhb, Khb, VTb, out, O2, ML);

    attn_combine<<<(MROWS * CDIM / 4) / 256, 256, 0, stream>>>(out, O2, ML);
}